// Round 1
// baseline (530.385 us; speedup 1.0000x reference)
//
#include <hip/hip_runtime.h>

// Pipeline: k_score -> k_topk (radix-select + bitonic) -> k_ioumat -> k_greedy (NMS) -> k_loss -> k_final
// Workspace need: ~5.72 MB.

static constexpr int NB   = 8;
static constexpr int NA   = 25200;
static constexpr int NCLS = 80;
static constexpr int CH   = 85;
static constexpr int NT   = 16;    // 8 clean + 8 patch tasks
static constexpr int KMAX = 1024;

// workspace byte offsets (all 16B aligned)
static constexpr size_t OFF_KEYS = 0;                                  // NT*NA*4   = 1,612,800
static constexpr size_t OFF_CLS  = OFF_KEYS + (size_t)NT * NA * 4;     // 1,612,800
static constexpr size_t OFF_BOX  = OFF_CLS  + (size_t)NT * NA * 4;     // NT*KMAX*16 = 262,144
static constexpr size_t OFF_CLSK = OFF_BOX  + (size_t)NT * KMAX * 16;  // 65,536
static constexpr size_t OFF_VALK = OFF_CLSK + (size_t)NT * KMAX * 4;   // 65,536
static constexpr size_t OFF_KEEP = OFF_VALK + (size_t)NT * KMAX * 4;   // NT*16*8 = 2,048
static constexpr size_t OFF_SUP  = OFF_KEEP + (size_t)NT * 16 * 8;     // NT*KMAX*16*8 = 2,097,152
static constexpr size_t OFF_PART = OFF_SUP  + (size_t)NT * KMAX * 16 * 8; // 64*2*4

__device__ __forceinline__ unsigned okey(float f) {
  unsigned u = __float_as_uint(f);
  return (u & 0x80000000u) ? ~u : (u | 0x80000000u);
}

// ---------------- K1: per-anchor score/class ----------------
__global__ __launch_bounds__(256) void k_score(const float* __restrict__ clean,
                                               const float* __restrict__ patch,
                                               unsigned* __restrict__ keys,
                                               int* __restrict__ clsArr) {
#pragma clang fp contract(off)
  const int t  = blockIdx.y;
  const int a0 = blockIdx.x * 128;
  const int nA = (NA - a0 < 128) ? (NA - a0) : 128;
  const float conf_th = (t < 8) ? 0.25f : 0.001f;
  const float* __restrict__ src = ((t < 8) ? clean : patch) + (size_t)(t & 7) * NA * CH;
  __shared__ float rows[128 * CH];
  // coalesced stage of 128 contiguous rows (nA*CH always %4==0, base 16B aligned)
  const float4* g4 = (const float4*)(src + (size_t)a0 * CH);
  float4* s4 = (float4*)rows;
  const int n4 = (nA * CH) >> 2;
  for (int i = threadIdx.x; i < n4; i += 256) s4[i] = g4[i];
  __syncthreads();
  if (threadIdx.x < nA) {
    const float* r = rows + threadIdx.x * CH;
    const float obj = r[4];
    float best = r[5] * obj;   // products first (matches ref argmax over cls_conf)
    int bc = 0;
    for (int c = 1; c < NCLS; ++c) {
      float v = r[5 + c] * obj;
      if (v > best) { best = v; bc = c; }
    }
    const bool valid = (obj > conf_th) && (best > conf_th);
    const float score = valid ? best : -1e30f;
    const int a = a0 + threadIdx.x;
    keys[(size_t)t * NA + a]   = okey(score);
    clsArr[(size_t)t * NA + a] = bc;
  }
}

// ---------------- K2: exact top-K (radix select + bitonic sort) ----------------
__global__ __launch_bounds__(256) void k_topk(const float* __restrict__ clean,
                                              const float* __restrict__ patch,
                                              const unsigned* __restrict__ keys,
                                              const int* __restrict__ clsArr,
                                              float* __restrict__ boxesK,
                                              int* __restrict__ clsK,
                                              int* __restrict__ validK) {
#pragma clang fp contract(off)
  const int t = blockIdx.x;
  const int K = (t < 8) ? 512 : 1024;
  const float conf_th = (t < 8) ? 0.25f : 0.001f;
  const unsigned* __restrict__ kk = keys + (size_t)t * NA;
  __shared__ unsigned hist[256];
  __shared__ unsigned s_sel[2];
  __shared__ unsigned s_cnt;
  __shared__ unsigned long long buf[2048];

  unsigned prefix = 0;
  unsigned remaining = (unsigned)K;
  for (int pass = 0; pass < 4; ++pass) {
    const int shift = 24 - 8 * pass;
    for (int b = threadIdx.x; b < 256; b += 256) hist[b] = 0;
    __syncthreads();
    for (int i = threadIdx.x; i < NA; i += 256) {
      unsigned key = kk[i];
      if ((pass == 0) || ((key >> (shift + 8)) == prefix))
        atomicAdd(&hist[(key >> shift) & 255u], 1u);
    }
    __syncthreads();
    if (threadIdx.x == 0) {
      unsigned acc = 0; int sel = 0;
      for (int b = 255; b >= 0; --b) {
        unsigned c = hist[b];
        if (acc + c >= remaining) { sel = b; break; }
        acc += c;
      }
      s_sel[0] = (prefix << 8) | (unsigned)sel;
      s_sel[1] = remaining - acc;
    }
    __syncthreads();
    prefix = s_sel[0];
    remaining = s_sel[1];
    __syncthreads();
  }
  const unsigned T = prefix;  // key value of K-th largest

  if (threadIdx.x == 0) s_cnt = 0;
  __syncthreads();
  for (int i = threadIdx.x; i < NA; i += 256) {
    unsigned key = kk[i];
    if (key >= T) {
      unsigned pos = atomicAdd(&s_cnt, 1u);
      if (pos < 2048u)
        buf[pos] = ((unsigned long long)key << 32) | (unsigned)(~(unsigned)i);
    }
  }
  __syncthreads();
  unsigned cnt = s_cnt; if (cnt > 2048u) cnt = 2048u;
  for (int i = (int)cnt + threadIdx.x; i < 2048; i += 256) buf[i] = 0ull;
  __syncthreads();
  // bitonic sort descending; tie -> larger ~idx (= smaller idx) first (top_k tie rule)
  for (int kk2 = 2; kk2 <= 2048; kk2 <<= 1) {
    for (int j = kk2 >> 1; j > 0; j >>= 1) {
      for (int i = threadIdx.x; i < 2048; i += 256) {
        int ixj = i ^ j;
        if (ixj > i) {
          unsigned long long a = buf[i], b = buf[ixj];
          bool desc = ((i & kk2) == 0);
          if (desc ? (a < b) : (a > b)) { buf[i] = b; buf[ixj] = a; }
        }
      }
      __syncthreads();
    }
  }
  // gather boxes/cls for top-K
  const float* __restrict__ src = ((t < 8) ? clean : patch) + (size_t)(t & 7) * NA * CH;
  const unsigned vkey = okey(conf_th);
  for (int k = threadIdx.x; k < K; k += 256) {
    unsigned long long v = buf[k];
    unsigned key = (unsigned)(v >> 32);
    int idx = (int)(~(unsigned)(v & 0xFFFFFFFFull));
    const float* r = src + (size_t)idx * CH;
    float cx = r[0], cy = r[1], w = r[2], h = r[3];
    float hw = w * 0.5f, hh = h * 0.5f;
    float* bo = boxesK + ((size_t)t * KMAX + k) * 4;
    bo[0] = cx - hw; bo[1] = cy - hh; bo[2] = cx + hw; bo[3] = cy + hh;
    clsK[t * KMAX + k]   = clsArr[(size_t)t * NA + idx];
    validK[t * KMAX + k] = (key > vkey) ? 1 : 0;
  }
}

// ---------------- K3a: suppression bit-matrix ----------------
__global__ __launch_bounds__(256) void k_ioumat(const float* __restrict__ boxesK,
                                                const int* __restrict__ clsK,
                                                unsigned long long* __restrict__ sup) {
#pragma clang fp contract(off)
  const int t  = blockIdx.y;
  const int K  = (t < 8) ? 512 : 1024;
  const int lw = (t < 8) ? 3 : 4;
  const int nw = 1 << lw;
  __shared__ float X1[KMAX], Y1[KMAX], X2[KMAX], Y2[KMAX], AR[KMAX];
  for (int i = threadIdx.x; i < K; i += 256) {
    const float* bo = boxesK + ((size_t)t * KMAX + i) * 4;
    float off = (float)clsK[t * KMAX + i] * 4096.0f;
    float x1 = bo[0] + off, y1 = bo[1] + off, x2 = bo[2] + off, y2 = bo[3] + off;
    X1[i] = x1; Y1[i] = y1; X2[i] = x2; Y2[i] = y2;
    AR[i] = (x2 - x1) * (y2 - y1);   // area from offset coords, same order as ref
  }
  __syncthreads();
  const int total = K * nw;
  unsigned long long* supt = sup + (size_t)t * (KMAX * 16);
  for (int widx = blockIdx.x * 256 + threadIdx.x; widx < total; widx += 16 * 256) {
    int i  = widx >> lw;
    int wc = widx & (nw - 1);
    float x1i = X1[i], y1i = Y1[i], x2i = X2[i], y2i = Y2[i], ai = AR[i];
    unsigned long long m = 0ull;
    int jbase = wc << 6;
    for (int l = 0; l < 64; ++l) {
      int j = jbase + l;
      if (j > i) {
        float tlx = fmaxf(x1i, X1[j]);
        float tly = fmaxf(y1i, Y1[j]);
        float brx = fminf(x2i, X2[j]);
        float bry = fminf(y2i, Y2[j]);
        float w = fmaxf(brx - tlx, 0.0f);
        float h = fmaxf(bry - tly, 0.0f);
        float inter = w * h;
        float uni = (ai + AR[j]) - inter;
        uni = (uni > 0.0f) ? uni : 1.0f;
        float iou = inter / uni;      // IEEE div, bit-matches ref compare
        if (iou > 0.45f) m |= (1ull << l);
      }
    }
    supt[(size_t)i * nw + wc] = m;
  }
}

// ---------------- K3b: greedy NMS, word-blocked (single wave / task) ----------------
__global__ __launch_bounds__(64) void k_greedy(const unsigned long long* __restrict__ sup,
                                               const int* __restrict__ validK,
                                               unsigned long long* __restrict__ keepw) {
  const int t  = blockIdx.x;
  const int K  = (t < 8) ? 512 : 1024;
  const int nw = K >> 6;
  const int lane = threadIdx.x;
  __shared__ unsigned long long buf[KMAX];  // one 64-row chunk: 64*nw u64
  const unsigned long long* base = sup + (size_t)t * (KMAX * 16);
  unsigned long long remv = 0ull;           // lane w: pending suppression for word w
  for (int W = 0; W < nw; ++W) {
    // stage rows [W*64, W*64+64) x nw words (contiguous) into LDS
    const uint4* g4 = (const uint4*)(base + (size_t)W * 64 * nw);
    uint4* b4 = (uint4*)buf;
    const int nq = nw >> 1;
    uint4 tmp[8];
#pragma unroll
    for (int q = 0; q < 8; ++q) if (q < nq) tmp[q] = g4[q * 64 + lane];
#pragma unroll
    for (int q = 0; q < 8; ++q) if (q < nq) b4[q * 64 + lane] = tmp[q];
    __syncthreads();
    int v = validK[t * KMAX + W * 64 + lane];
    unsigned long long cur = __ballot(v != 0);
    cur &= ~__shfl(remv, W);
    // in-word sequential greedy (uniform across lanes, pure-register chain)
#pragma unroll
    for (int r = 0; r < 64; ++r) {
      unsigned long long msk = 0ull - ((cur >> r) & 1ull);
      cur &= ~(buf[r * nw + W] & msk);
    }
    // forward suppression to later words, lane-parallel
    if (lane > W && lane < nw) {
      for (int r = 0; r < 64; ++r) {
        if ((cur >> r) & 1ull) remv |= buf[r * nw + lane];
      }
    }
    if (lane == 0) keepw[t * 16 + W] = cur;
    __syncthreads();
  }
}

// ---------------- K4: masked-max IoU loss partials ----------------
__global__ __launch_bounds__(256) void k_loss(const float* __restrict__ boxesK,
                                              const int* __restrict__ clsK,
                                              const unsigned long long* __restrict__ keepw,
                                              float* __restrict__ part) {
#pragma clang fp contract(off)
  const int img = blockIdx.y;
  const int chunk = blockIdx.x;
  const int tp = 8 + img;
  __shared__ float px1[KMAX], py1[KMAX], px2[KMAX], py2[KMAX], pa[KMAX];
  __shared__ int pcls[KMAX];
  __shared__ float red[256];
  for (int j = threadIdx.x; j < KMAX; j += 256) {
    const float* bo = boxesK + ((size_t)tp * KMAX + j) * 4;
    float x1 = bo[0] / 640.0f, y1 = bo[1] / 640.0f;
    float x2 = bo[2] / 640.0f, y2 = bo[3] / 640.0f;
    px1[j] = x1; py1[j] = y1; px2[j] = x2; py2[j] = y2;
    pa[j] = (x2 - x1) * (y2 - y1);
    int kept = (int)((keepw[tp * 16 + (j >> 6)] >> (j & 63)) & 1ull);
    pcls[j] = kept ? clsK[tp * KMAX + j] : -1;
  }
  __syncthreads();
  const int row = chunk * 64 + (threadIdx.x & 63);   // < 512
  const int stripe = threadIdx.x >> 6;
  const int ck = (int)((keepw[img * 16 + (row >> 6)] >> (row & 63)) & 1ull);
  const float* bo = boxesK + ((size_t)img * KMAX + row) * 4;
  float cx1 = bo[0] / 640.0f, cy1 = bo[1] / 640.0f;
  float cx2 = bo[2] / 640.0f, cy2 = bo[3] / 640.0f;
  float ca = (cx2 - cx1) * (cy2 - cy1);
  const int ccls = clsK[img * KMAX + row];
  float m = 0.0f;
  if (ck) {
    const int j0 = stripe * 256;
    for (int j = j0; j < j0 + 256; ++j) {
      if (pcls[j] == ccls) {
        float tlx = fmaxf(cx1, px1[j]);
        float tly = fmaxf(cy1, py1[j]);
        float brx = fminf(cx2, px2[j]);
        float bry = fminf(cy2, py2[j]);
        float w = fmaxf(brx - tlx, 0.0f);
        float h = fmaxf(bry - tly, 0.0f);
        float inter = w * h;
        float uni = (ca + pa[j]) - inter;
        uni = (uni > 0.0f) ? uni : 1.0f;
        m = fmaxf(m, inter / uni);
      }
    }
  }
  red[threadIdx.x] = m;
  __syncthreads();
  if (threadIdx.x < 64) {
    float mm = fmaxf(fmaxf(red[threadIdx.x], red[threadIdx.x + 64]),
                     fmaxf(red[threadIdx.x + 128], red[threadIdx.x + 192]));
    float sv = ck ? mm : 0.0f;
    float nv = ck ? 1.0f : 0.0f;
    for (int off = 32; off > 0; off >>= 1) {
      sv += __shfl_down(sv, off);
      nv += __shfl_down(nv, off);
    }
    if (threadIdx.x == 0) {
      int b = img * 8 + chunk;
      part[b * 2 + 0] = sv;
      part[b * 2 + 1] = nv;
    }
  }
}

// ---------------- K5: deterministic final reduce ----------------
__global__ __launch_bounds__(64) void k_final(const float* __restrict__ part,
                                              float* __restrict__ out) {
  int lane = threadIdx.x;
  float sv = part[lane * 2 + 0];
  float nv = part[lane * 2 + 1];
  for (int off = 32; off > 0; off >>= 1) {
    sv += __shfl_down(sv, off);
    nv += __shfl_down(nv, off);
  }
  if (lane == 0) out[0] = (nv > 0.0f) ? (1.0f - sv / fmaxf(nv, 1.0f)) : 1.0f;
}

extern "C" void kernel_launch(void* const* d_in, const int* in_sizes, int n_in,
                              void* d_out, int out_size, void* d_ws, size_t ws_size,
                              hipStream_t stream) {
  const float* clean = (const float*)d_in[0];
  const float* patch = (const float*)d_in[1];
  char* ws = (char*)d_ws;
  unsigned* keys            = (unsigned*)(ws + OFF_KEYS);
  int* clsArr               = (int*)(ws + OFF_CLS);
  float* boxesK             = (float*)(ws + OFF_BOX);
  int* clsK                 = (int*)(ws + OFF_CLSK);
  int* validK               = (int*)(ws + OFF_VALK);
  unsigned long long* keepw = (unsigned long long*)(ws + OFF_KEEP);
  unsigned long long* sup   = (unsigned long long*)(ws + OFF_SUP);
  float* part               = (float*)(ws + OFF_PART);
  float* out                = (float*)d_out;

  k_score <<<dim3((NA + 127) / 128, NT), 256, 0, stream>>>(clean, patch, keys, clsArr);
  k_topk  <<<NT, 256, 0, stream>>>(clean, patch, keys, clsArr, boxesK, clsK, validK);
  k_ioumat<<<dim3(16, NT), 256, 0, stream>>>(boxesK, clsK, sup);
  k_greedy<<<NT, 64, 0, stream>>>(sup, validK, keepw);
  k_loss  <<<dim3(8, NB), 256, 0, stream>>>(boxesK, clsK, keepw, part);
  k_final <<<1, 64, 0, stream>>>(part, out);
}